// Round 1
// baseline (5308.208 us; speedup 1.0000x reference)
//
#include <hip/hip_runtime.h>
#include <math.h>

// ---------------------------------------------------------------------------
// AxialLongShortTransformer — fp32 reference-correct implementation.
// x: (1,128,192,192). DEPTH=2 layers x {attn along H, attn along W, convFFN}.
// ---------------------------------------------------------------------------

#define SP 36864            // 192*192 spatial
#define TT 192              // sequence length per attention
#define NC 128              // model dim
#define NHEAD 8
#define DHEAD 32

// ---------------- LayerNorm over channel for attention input ----------------
// perm==0: row=(b,t), X addr = c*SP + t*192 + b   (b=W coord, t=H coord)
// perm==1: row=(b,t), X addr = c*SP + b*192 + t   (b=H coord, t=W coord)
__global__ __launch_bounds__(256) void ln_rows_kernel(
    const float* __restrict__ X, const float* __restrict__ g,
    const float* __restrict__ b, float* __restrict__ XN, int perm)
{
    int gid = blockIdx.x * 256 + threadIdx.x;      // 0..36863
    int i0 = gid % 192, i1 = gid / 192;
    int sp_off = i1 * 192 + i0;                    // coalesced along i0
    int row = (perm == 0) ? (i0 * 192 + i1) : (i1 * 192 + i0);   // b*192+t
    float sum = 0.f, sumsq = 0.f;
    for (int c = 0; c < NC; ++c) {
        float v = X[(size_t)c * SP + sp_off];
        sum += v; sumsq += v * v;
    }
    float mu  = sum * (1.f / NC);
    float var = sumsq * (1.f / NC) - mu * mu;
    float rs  = rsqrtf(var + 1e-5f);
    float* xr = XN + (size_t)row * NC;
    for (int c = 0; c < NC; ++c) {
        float v = X[(size_t)c * SP + sp_off];
        xr[c] = (v - mu) * rs * g[c] + b[c];
    }
}

// ---------------- generic fp32 GEMM, 64x64 tile, BK=32 ----------------------
// C = A(M,K) @ B(K,N); epilogue modes:
//  0: Q     -> O0[((m/192)*8 + n/32)*6144 + (m%192)*32 + (n&31)] = acc*scale
//  1: KV    -> n<256 into O0 (K), n>=256 into O1 (V), same (b,h,t,d) scatter
//  2: OutPr -> +bias[n]; write X: perm0 X[n*SP + t*192 + b], perm1 X[n*SP + b*192 + t]
__global__ __launch_bounds__(256) void gemm_kernel(
    const float* __restrict__ A, const float* __restrict__ B, int K, int N,
    int mode, float scale, const float* __restrict__ bias,
    float* __restrict__ O0, float* __restrict__ O1, int perm)
{
    __shared__ float As[32][64];   // [k][m]
    __shared__ float Bs[32][64];   // [k][n]
    int m0 = blockIdx.y * 64, n0 = blockIdx.x * 64;
    int tid = threadIdx.x;
    int tx = tid & 15, ty = tid >> 4;
    float acc[4][4] = {};
    for (int k0 = 0; k0 < K; k0 += 32) {
        #pragma unroll
        for (int f = tid; f < 512; f += 256) {
            int m = f >> 3, kq = f & 7;
            float4 av = *(const float4*)(A + (size_t)(m0 + m) * K + k0 + kq * 4);
            As[kq * 4 + 0][m] = av.x; As[kq * 4 + 1][m] = av.y;
            As[kq * 4 + 2][m] = av.z; As[kq * 4 + 3][m] = av.w;
        }
        #pragma unroll
        for (int f = tid; f < 512; f += 256) {
            int kk = f >> 4, nq = f & 15;
            *(float4*)&Bs[kk][nq * 4] =
                *(const float4*)(B + (size_t)(k0 + kk) * N + n0 + nq * 4);
        }
        __syncthreads();
        #pragma unroll 8
        for (int kk = 0; kk < 32; ++kk) {
            float4 a4 = *(const float4*)&As[kk][ty * 4];
            float4 b4 = *(const float4*)&Bs[kk][tx * 4];
            float av[4] = {a4.x, a4.y, a4.z, a4.w};
            float bv[4] = {b4.x, b4.y, b4.z, b4.w};
            #pragma unroll
            for (int i = 0; i < 4; ++i)
                #pragma unroll
                for (int j = 0; j < 4; ++j) acc[i][j] += av[i] * bv[j];
        }
        __syncthreads();
    }
    #pragma unroll
    for (int i = 0; i < 4; ++i) {
        int m = m0 + ty * 4 + i;
        int bq = m / 192, t = m % 192;
        #pragma unroll
        for (int j = 0; j < 4; ++j) {
            int n = n0 + tx * 4 + j;
            float v = acc[i][j];
            if (mode == 0) {
                O0[(size_t)(bq * 8 + (n >> 5)) * 6144 + t * 32 + (n & 31)] = v * scale;
            } else if (mode == 1) {
                float* dst = (n < 256) ? O0 : O1;
                int nn = n & 255;
                dst[(size_t)(bq * 8 + (nn >> 5)) * 6144 + t * 32 + (nn & 31)] = v;
            } else {
                v += bias[n];
                int sp = (perm == 0) ? (t * 192 + bq) : (bq * 192 + t);
                O0[(size_t)n * SP + sp] = v;
            }
        }
    }
}

// ------------- dynamic projection softmax + global landmark (r=1) -----------
__global__ __launch_bounds__(256) void proj_gkv_kernel(
    const float* __restrict__ Kb, const float* __restrict__ Vb,
    const float* __restrict__ wp, const float* __restrict__ lng_g,
    const float* __restrict__ lng_b, float* __restrict__ GK, float* __restrict__ GV)
{
    int bh = blockIdx.x;
    const float* kb = Kb + (size_t)bh * 6144;
    const float* vb = Vb + (size_t)bh * 6144;
    __shared__ float wps[32], sc[192], red[1], gkr[32];
    int tid = threadIdx.x;
    if (tid < 32) wps[tid] = wp[tid];
    __syncthreads();
    if (tid < 192) {
        float s = 0.f;
        for (int d = 0; d < 32; ++d) s += kb[tid * 32 + d] * wps[d];
        sc[tid] = s;
    }
    __syncthreads();
    if (tid < 64) {
        float m = fmaxf(fmaxf(sc[tid], sc[tid + 64]), sc[tid + 128]);
        for (int o = 32; o; o >>= 1) m = fmaxf(m, __shfl_xor(m, o));
        if (tid == 0) red[0] = m;
    }
    __syncthreads();
    float mx = red[0];
    if (tid < 192) sc[tid] = __expf(sc[tid] - mx);
    __syncthreads();
    if (tid < 64) {
        float s = sc[tid] + sc[tid + 64] + sc[tid + 128];
        for (int o = 32; o; o >>= 1) s += __shfl_xor(s, o);
        if (tid == 0) red[0] = s;
    }
    __syncthreads();
    float inv = 1.f / red[0];
    if (tid < 192) sc[tid] *= inv;
    __syncthreads();
    if (tid < 32) {
        float ka = 0.f, va = 0.f;
        for (int t = 0; t < 192; ++t) {
            float p = sc[t];
            ka += p * kb[t * 32 + tid];
            va += p * vb[t * 32 + tid];
        }
        gkr[tid] = ka;
        GV[(size_t)bh * 32 + tid] = va;
    }
    __syncthreads();
    if (tid < 32) {
        float mu = 0.f;
        for (int d = 0; d < 32; ++d) mu += gkr[d];
        mu *= (1.f / 32);
        float var = 0.f;
        for (int d = 0; d < 32; ++d) { float df = gkr[d] - mu; var += df * df; }
        var *= (1.f / 32);
        float rs = rsqrtf(var + 1e-5f);
        GK[(size_t)bh * 32 + tid] = (gkr[tid] - mu) * rs * lng_g[tid] + lng_b[tid];
    }
}

// ---------------- LayerNorm(k) over d=32 in-place ---------------------------
__global__ __launch_bounds__(256) void lkln_kernel(
    float* __restrict__ Kb, const float* __restrict__ g, const float* __restrict__ b)
{
    int tid = threadIdx.x;
    size_t row = (size_t)blockIdx.x * 8 + (tid >> 5);
    int d = tid & 31;
    float v = Kb[row * 32 + d];
    float s = v;
    for (int o = 16; o; o >>= 1) s += __shfl_xor(s, o, 32);
    float mu = s * (1.f / 32);
    float df = v - mu, vv = df * df;
    for (int o = 16; o; o >>= 1) vv += __shfl_xor(vv, o, 32);
    float rs = rsqrtf(vv * (1.f / 32) + 1e-5f);
    Kb[row * 32 + d] = df * rs * g[d] + b[d];
}

// ---------------- windowed attention + global landmark ----------------------
// block per (b,h): 192 threads, one query each; K/V staged in LDS.
__global__ __launch_bounds__(192) void attn_kernel(
    const float* __restrict__ Q, const float* __restrict__ Kb,
    const float* __restrict__ Vb, const float* __restrict__ GK,
    const float* __restrict__ GV, float* __restrict__ AO)
{
    __shared__ float ks[192 * 32], vs[192 * 32], gks[32], gvs[32];
    int bh = blockIdx.x;
    int tid = threadIdx.x;
    size_t base = (size_t)bh * 6144;
    for (int f = tid; f < 1536; f += 192) {
        ((float4*)ks)[f] = ((const float4*)(Kb + base))[f];
        ((float4*)vs)[f] = ((const float4*)(Vb + base))[f];
    }
    if (tid < 32) gks[tid] = GK[(size_t)bh * 32 + tid];
    else if (tid < 64) gvs[tid - 32] = GV[(size_t)bh * 32 + tid - 32];
    __syncthreads();

    float q[32];
    const float* qp = Q + base + tid * 32;
    #pragma unroll
    for (int d = 0; d < 32; ++d) q[d] = qp[d];

    float m = 0.f;
    #pragma unroll
    for (int d = 0; d < 32; ++d) m += q[d] * gks[d];
    float l = 1.f;
    float out[32];
    #pragma unroll
    for (int d = 0; d < 32; ++d) out[d] = gvs[d];

    int w = tid >> 6;
    int lo = (w == 0) ? 0 : (w - 1) * 64;
    int hi = (w == 2) ? 192 : (w + 2) * 64;
    for (int j = lo; j < hi; ++j) {
        const float* kr = ks + j * 32;
        float s = 0.f;
        #pragma unroll
        for (int d = 0; d < 32; ++d) s += q[d] * kr[d];
        const float* vr = vs + j * 32;
        if (s > m) {
            float scl = __expf(m - s);
            l = l * scl + 1.f;
            #pragma unroll
            for (int d = 0; d < 32; ++d) out[d] = out[d] * scl + vr[d];
            m = s;
        } else {
            float p = __expf(s - m);
            l += p;
            #pragma unroll
            for (int d = 0; d < 32; ++d) out[d] += p * vr[d];
        }
    }
    float inv = 1.f / l;
    int b = bh >> 3, h = bh & 7;
    float* op = AO + ((size_t)b * 192 + tid) * 256 + h * 32;
    #pragma unroll
    for (int d = 0; d < 32; ++d) op[d] = out[d] * inv;
}

// ---------------- channel LayerNorm for conv FFN ----------------------------
__global__ __launch_bounds__(256) void chanln_kernel(
    const float* __restrict__ X, const float* __restrict__ g,
    const float* __restrict__ b, float* __restrict__ XN)
{
    int pos = blockIdx.x * 256 + threadIdx.x;
    float sum = 0.f, sumsq = 0.f;
    for (int c = 0; c < NC; ++c) {
        float v = X[(size_t)c * SP + pos];
        sum += v; sumsq += v * v;
    }
    float mu  = sum * (1.f / NC);
    float var = sumsq * (1.f / NC) - mu * mu;
    float inv = 1.f / (sqrtf(fmaxf(var, 0.f)) + 1e-5f);
    for (int c = 0; c < NC; ++c) {
        float v = X[(size_t)c * SP + pos];
        XN[(size_t)c * SP + pos] = (v - mu) * inv * g[c] + b[c];
    }
}

// ---------------- direct 3x3 conv, SAME, optional leaky ---------------------
// block: 64 co x 64 x positions, one y row. thread: 4co x 4x.
__global__ __launch_bounds__(256) void conv3x3_kernel(
    const float* __restrict__ in, const float* __restrict__ w,
    const float* __restrict__ bias, float* __restrict__ out, int CI, int leaky)
{
    __shared__ float in_s[8][3][66];
    __shared__ float ws_s[8][64 * 9];
    int x0  = blockIdx.x * 64;
    int y   = blockIdx.y;
    int co0 = blockIdx.z * 64;
    int tid = threadIdx.x;
    int xq = tid & 15, coq = tid >> 4;
    float acc[4][4] = {};
    int nch = CI >> 3;
    for (int cc = 0; cc < nch; ++cc) {
        for (int idx = tid; idx < 1584; idx += 256) {
            int ci = idx / 198, r = idx % 198, yy = r / 66, xx = r % 66;
            int gy = y + yy - 1, gx = x0 + xx - 1;
            float v = 0.f;
            if (gy >= 0 && gy < 192 && (unsigned)gx < 192u)
                v = in[(size_t)(cc * 8 + ci) * SP + gy * 192 + gx];
            in_s[ci][yy][xx] = v;
        }
        for (int idx = tid; idx < 4608; idx += 256) {
            int co = idx / 72, r2 = idx % 72, ci = r2 / 9, k = r2 % 9;
            ws_s[ci][co * 9 + k] = w[((size_t)(co0 + co) * CI + cc * 8 + ci) * 9 + k];
        }
        __syncthreads();
        #pragma unroll
        for (int ci = 0; ci < 8; ++ci) {
            float iv[3][6];
            #pragma unroll
            for (int yy = 0; yy < 3; ++yy)
                #pragma unroll
                for (int xx = 0; xx < 6; ++xx) iv[yy][xx] = in_s[ci][yy][xq * 4 + xx];
            #pragma unroll
            for (int c4 = 0; c4 < 4; ++c4) {
                const float* wp = &ws_s[ci][(coq * 4 + c4) * 9];
                float w9[9];
                #pragma unroll
                for (int k = 0; k < 9; ++k) w9[k] = wp[k];
                #pragma unroll
                for (int x4 = 0; x4 < 4; ++x4) {
                    float s = acc[c4][x4];
                    #pragma unroll
                    for (int ky = 0; ky < 3; ++ky)
                        #pragma unroll
                        for (int kx = 0; kx < 3; ++kx)
                            s += w9[ky * 3 + kx] * iv[ky][x4 + kx];
                    acc[c4][x4] = s;
                }
            }
        }
        __syncthreads();
    }
    #pragma unroll
    for (int c4 = 0; c4 < 4; ++c4) {
        int co = co0 + coq * 4 + c4;
        float bb = bias[co];
        #pragma unroll
        for (int x4 = 0; x4 < 4; ++x4) {
            float v = acc[c4][x4] + bb;
            if (leaky) v = (v >= 0.f) ? v : 0.01f * v;
            out[(size_t)co * SP + y * 192 + x0 + xq * 4 + x4] = v;
        }
    }
}

// ---------------------------------------------------------------------------
extern "C" void kernel_launch(void* const* d_in, const int* in_sizes, int n_in,
                              void* d_out, int out_size, void* d_ws, size_t ws_size,
                              hipStream_t stream)
{
    const float* x_in    = (const float*)d_in[0];
    const float* ln_g    = (const float*)d_in[1];
    const float* ln_b    = (const float*)d_in[2];
    const float* Wq      = (const float*)d_in[3];
    const float* Wkv     = (const float*)d_in[4];
    const float* Wproj   = (const float*)d_in[5];
    const float* lnl_g   = (const float*)d_in[6];
    const float* lnl_b   = (const float*)d_in[7];
    const float* lng_g   = (const float*)d_in[8];
    const float* lng_b   = (const float*)d_in[9];
    const float* Wo      = (const float*)d_in[10];
    const float* bo      = (const float*)d_in[11];
    const float* cln_g   = (const float*)d_in[12];
    const float* cln_b   = (const float*)d_in[13];
    const float* conv1_w = (const float*)d_in[14];
    const float* conv1_b = (const float*)d_in[15];
    const float* conv2_w = (const float*)d_in[16];
    const float* conv2_b = (const float*)d_in[17];

    float* X = (float*)d_out;                   // running activation, 18.87 MB
    char* ws = (char*)d_ws;
    const size_t SZ_AO = 37748736;              // (36864,256) f32
    float* AO  = (float*)(ws);                  // attn out; first half doubles as XN
    float* XN  = AO;                            // (36864,128): dead when AO written
    float* Qb  = (float*)(ws + SZ_AO);
    float* Kb  = Qb + 9437184;
    float* Vb  = Kb + 9437184;
    float* GK  = Vb + 9437184;
    float* GV  = GK + 49152;
    float* HID = Qb;                            // conv hidden (512,192,192) = Q+K
    float* XNc = AO;                            // conv LN out (128,192,192)

    hipMemcpyAsync(X, x_in, (size_t)SP * NC * 4, hipMemcpyDeviceToDevice, stream);

    const float qscale = 0.17677669529663687f;  // 32^-0.5

    for (int l = 0; l < 2; ++l) {
        for (int a = 0; a < 2; ++a) {
            int la = l * 2 + a;
            ln_rows_kernel<<<144, 256, 0, stream>>>(X, ln_g + la * 128, ln_b + la * 128, XN, a);
            gemm_kernel<<<dim3(4, 576), 256, 0, stream>>>(
                XN, Wq + (size_t)la * 128 * 256, 128, 256, 0, qscale, nullptr, Qb, nullptr, a);
            gemm_kernel<<<dim3(8, 576), 256, 0, stream>>>(
                XN, Wkv + (size_t)la * 128 * 512, 128, 512, 1, 1.f, nullptr, Kb, Vb, a);
            proj_gkv_kernel<<<1536, 256, 0, stream>>>(
                Kb, Vb, Wproj + la * 32, lng_g + la * 32, lng_b + la * 32, GK, GV);
            lkln_kernel<<<36864, 256, 0, stream>>>(Kb, lnl_g + la * 32, lnl_b + la * 32);
            attn_kernel<<<1536, 192, 0, stream>>>(Qb, Kb, Vb, GK, GV, AO);
            gemm_kernel<<<dim3(2, 576), 256, 0, stream>>>(
                AO, Wo + (size_t)la * 256 * 128, 256, 128, 2, 1.f, bo + la * 128, X, nullptr, a);
        }
        chanln_kernel<<<144, 256, 0, stream>>>(X, cln_g + l * 128, cln_b + l * 128, XNc);
        conv3x3_kernel<<<dim3(3, 192, 8), 256, 0, stream>>>(
            XNc, conv1_w + (size_t)l * 512 * 128 * 9, conv1_b + l * 512, HID, 128, 1);
        conv3x3_kernel<<<dim3(3, 192, 2), 256, 0, stream>>>(
            HID, conv2_w + (size_t)l * 128 * 512 * 9, conv2_b + l * 128, X, 512, 0);
    }
}

// Round 2
// 2325.079 us; speedup vs baseline: 2.2830x; 2.2830x over previous
//
#include <hip/hip_runtime.h>
#include <math.h>

// ---------------------------------------------------------------------------
// AxialLongShortTransformer — attn path fp32 (unchanged), conv FFN on bf16 MFMA.
// ---------------------------------------------------------------------------

#define SP 36864            // 192*192 spatial
#define NC 128              // model dim

typedef __attribute__((ext_vector_type(8))) short short8v;   // 8 bf16 (4 VGPRs)
typedef __attribute__((ext_vector_type(4))) float f32x4;

static __device__ __forceinline__ unsigned short bf16r(float f) {
    unsigned u = __builtin_bit_cast(unsigned, f);
    u += 0x7fffu + ((u >> 16) & 1u);            // round-to-nearest-even
    return (unsigned short)(u >> 16);
}

// ---------------- LayerNorm over channel for attention input ----------------
__global__ __launch_bounds__(256) void ln_rows_kernel(
    const float* __restrict__ X, const float* __restrict__ g,
    const float* __restrict__ b, float* __restrict__ XN, int perm)
{
    int gid = blockIdx.x * 256 + threadIdx.x;      // 0..36863
    int i0 = gid % 192, i1 = gid / 192;
    int sp_off = i1 * 192 + i0;                    // coalesced along i0
    int row = (perm == 0) ? (i0 * 192 + i1) : (i1 * 192 + i0);   // b*192+t
    float sum = 0.f, sumsq = 0.f;
    for (int c = 0; c < NC; ++c) {
        float v = X[(size_t)c * SP + sp_off];
        sum += v; sumsq += v * v;
    }
    float mu  = sum * (1.f / NC);
    float var = sumsq * (1.f / NC) - mu * mu;
    float rs  = rsqrtf(var + 1e-5f);
    float* xr = XN + (size_t)row * NC;
    for (int c = 0; c < NC; ++c) {
        float v = X[(size_t)c * SP + sp_off];
        xr[c] = (v - mu) * rs * g[c] + b[c];
    }
}

// ---------------- generic fp32 GEMM, 64x64 tile, BK=32 ----------------------
__global__ __launch_bounds__(256) void gemm_kernel(
    const float* __restrict__ A, const float* __restrict__ B, int K, int N,
    int mode, float scale, const float* __restrict__ bias,
    float* __restrict__ O0, float* __restrict__ O1, int perm)
{
    __shared__ float As[32][64];   // [k][m]
    __shared__ float Bs[32][64];   // [k][n]
    int m0 = blockIdx.y * 64, n0 = blockIdx.x * 64;
    int tid = threadIdx.x;
    int tx = tid & 15, ty = tid >> 4;
    float acc[4][4] = {};
    for (int k0 = 0; k0 < K; k0 += 32) {
        #pragma unroll
        for (int f = tid; f < 512; f += 256) {
            int m = f >> 3, kq = f & 7;
            float4 av = *(const float4*)(A + (size_t)(m0 + m) * K + k0 + kq * 4);
            As[kq * 4 + 0][m] = av.x; As[kq * 4 + 1][m] = av.y;
            As[kq * 4 + 2][m] = av.z; As[kq * 4 + 3][m] = av.w;
        }
        #pragma unroll
        for (int f = tid; f < 512; f += 256) {
            int kk = f >> 4, nq = f & 15;
            *(float4*)&Bs[kk][nq * 4] =
                *(const float4*)(B + (size_t)(k0 + kk) * N + n0 + nq * 4);
        }
        __syncthreads();
        #pragma unroll 8
        for (int kk = 0; kk < 32; ++kk) {
            float4 a4 = *(const float4*)&As[kk][ty * 4];
            float4 b4 = *(const float4*)&Bs[kk][tx * 4];
            float av[4] = {a4.x, a4.y, a4.z, a4.w};
            float bv[4] = {b4.x, b4.y, b4.z, b4.w};
            #pragma unroll
            for (int i = 0; i < 4; ++i)
                #pragma unroll
                for (int j = 0; j < 4; ++j) acc[i][j] += av[i] * bv[j];
        }
        __syncthreads();
    }
    #pragma unroll
    for (int i = 0; i < 4; ++i) {
        int m = m0 + ty * 4 + i;
        int bq = m / 192, t = m % 192;
        #pragma unroll
        for (int j = 0; j < 4; ++j) {
            int n = n0 + tx * 4 + j;
            float v = acc[i][j];
            if (mode == 0) {
                O0[(size_t)(bq * 8 + (n >> 5)) * 6144 + t * 32 + (n & 31)] = v * scale;
            } else if (mode == 1) {
                float* dst = (n < 256) ? O0 : O1;
                int nn = n & 255;
                dst[(size_t)(bq * 8 + (nn >> 5)) * 6144 + t * 32 + (nn & 31)] = v;
            } else {
                v += bias[n];
                int sp = (perm == 0) ? (t * 192 + bq) : (bq * 192 + t);
                O0[(size_t)n * SP + sp] = v;
            }
        }
    }
}

// ------------- dynamic projection softmax + global landmark (r=1) -----------
__global__ __launch_bounds__(256) void proj_gkv_kernel(
    const float* __restrict__ Kb, const float* __restrict__ Vb,
    const float* __restrict__ wp, const float* __restrict__ lng_g,
    const float* __restrict__ lng_b, float* __restrict__ GK, float* __restrict__ GV)
{
    int bh = blockIdx.x;
    const float* kb = Kb + (size_t)bh * 6144;
    const float* vb = Vb + (size_t)bh * 6144;
    __shared__ float wps[32], sc[192], red[1], gkr[32];
    int tid = threadIdx.x;
    if (tid < 32) wps[tid] = wp[tid];
    __syncthreads();
    if (tid < 192) {
        float s = 0.f;
        for (int d = 0; d < 32; ++d) s += kb[tid * 32 + d] * wps[d];
        sc[tid] = s;
    }
    __syncthreads();
    if (tid < 64) {
        float m = fmaxf(fmaxf(sc[tid], sc[tid + 64]), sc[tid + 128]);
        for (int o = 32; o; o >>= 1) m = fmaxf(m, __shfl_xor(m, o));
        if (tid == 0) red[0] = m;
    }
    __syncthreads();
    float mx = red[0];
    if (tid < 192) sc[tid] = __expf(sc[tid] - mx);
    __syncthreads();
    if (tid < 64) {
        float s = sc[tid] + sc[tid + 64] + sc[tid + 128];
        for (int o = 32; o; o >>= 1) s += __shfl_xor(s, o);
        if (tid == 0) red[0] = s;
    }
    __syncthreads();
    float inv = 1.f / red[0];
    if (tid < 192) sc[tid] *= inv;
    __syncthreads();
    if (tid < 32) {
        float ka = 0.f, va = 0.f;
        for (int t = 0; t < 192; ++t) {
            float p = sc[t];
            ka += p * kb[t * 32 + tid];
            va += p * vb[t * 32 + tid];
        }
        gkr[tid] = ka;
        GV[(size_t)bh * 32 + tid] = va;
    }
    __syncthreads();
    if (tid < 32) {
        float mu = 0.f;
        for (int d = 0; d < 32; ++d) mu += gkr[d];
        mu *= (1.f / 32);
        float var = 0.f;
        for (int d = 0; d < 32; ++d) { float df = gkr[d] - mu; var += df * df; }
        var *= (1.f / 32);
        float rs = rsqrtf(var + 1e-5f);
        GK[(size_t)bh * 32 + tid] = (gkr[tid] - mu) * rs * lng_g[tid] + lng_b[tid];
    }
}

// ---------------- LayerNorm(k) over d=32 in-place ---------------------------
__global__ __launch_bounds__(256) void lkln_kernel(
    float* __restrict__ Kb, const float* __restrict__ g, const float* __restrict__ b)
{
    int tid = threadIdx.x;
    size_t row = (size_t)blockIdx.x * 8 + (tid >> 5);
    int d = tid & 31;
    float v = Kb[row * 32 + d];
    float s = v;
    for (int o = 16; o; o >>= 1) s += __shfl_xor(s, o, 32);
    float mu = s * (1.f / 32);
    float df = v - mu, vv = df * df;
    for (int o = 16; o; o >>= 1) vv += __shfl_xor(vv, o, 32);
    float rs = rsqrtf(vv * (1.f / 32) + 1e-5f);
    Kb[row * 32 + d] = df * rs * g[d] + b[d];
}

// ---------------- windowed attention + global landmark ----------------------
__global__ __launch_bounds__(192) void attn_kernel(
    const float* __restrict__ Q, const float* __restrict__ Kb,
    const float* __restrict__ Vb, const float* __restrict__ GK,
    const float* __restrict__ GV, float* __restrict__ AO)
{
    __shared__ float ks[192 * 32], vs[192 * 32], gks[32], gvs[32];
    int bh = blockIdx.x;
    int tid = threadIdx.x;
    size_t base = (size_t)bh * 6144;
    for (int f = tid; f < 1536; f += 192) {
        ((float4*)ks)[f] = ((const float4*)(Kb + base))[f];
        ((float4*)vs)[f] = ((const float4*)(Vb + base))[f];
    }
    if (tid < 32) gks[tid] = GK[(size_t)bh * 32 + tid];
    else if (tid < 64) gvs[tid - 32] = GV[(size_t)bh * 32 + tid - 32];
    __syncthreads();

    float q[32];
    const float* qp = Q + base + tid * 32;
    #pragma unroll
    for (int d = 0; d < 32; ++d) q[d] = qp[d];

    float m = 0.f;
    #pragma unroll
    for (int d = 0; d < 32; ++d) m += q[d] * gks[d];
    float l = 1.f;
    float out[32];
    #pragma unroll
    for (int d = 0; d < 32; ++d) out[d] = gvs[d];

    int w = tid >> 6;
    int lo = (w == 0) ? 0 : (w - 1) * 64;
    int hi = (w == 2) ? 192 : (w + 2) * 64;
    for (int j = lo; j < hi; ++j) {
        const float* kr = ks + j * 32;
        float s = 0.f;
        #pragma unroll
        for (int d = 0; d < 32; ++d) s += q[d] * kr[d];
        const float* vr = vs + j * 32;
        if (s > m) {
            float scl = __expf(m - s);
            l = l * scl + 1.f;
            #pragma unroll
            for (int d = 0; d < 32; ++d) out[d] = out[d] * scl + vr[d];
            m = s;
        } else {
            float p = __expf(s - m);
            l += p;
            #pragma unroll
            for (int d = 0; d < 32; ++d) out[d] += p * vr[d];
        }
    }
    float inv = 1.f / l;
    int b = bh >> 3, h = bh & 7;
    float* op = AO + ((size_t)b * 192 + tid) * 256 + h * 32;
    #pragma unroll
    for (int d = 0; d < 32; ++d) op[d] = out[d] * inv;
}

// -------- ChanLayerNorm -> bf16 [sp][128] (conv1 input, transposed) ---------
__global__ __launch_bounds__(256) void chanln_bf16_kernel(
    const float* __restrict__ X, const float* __restrict__ g,
    const float* __restrict__ b, unsigned short* __restrict__ out)
{
    int tid = threadIdx.x;
    int p = tid >> 2, qc = tid & 3;
    int pos = blockIdx.x * 64 + p;
    float xv[32];
    float sum = 0.f, sumsq = 0.f;
    #pragma unroll
    for (int c = 0; c < 32; ++c) {
        float v = X[(size_t)(qc * 32 + c) * SP + pos];
        xv[c] = v; sum += v; sumsq += v * v;
    }
    sum += __shfl_xor(sum, 1);  sum += __shfl_xor(sum, 2);
    sumsq += __shfl_xor(sumsq, 1); sumsq += __shfl_xor(sumsq, 2);
    float mu  = sum * (1.f / 128);
    float var = sumsq * (1.f / 128) - mu * mu;
    float inv = 1.f / (sqrtf(fmaxf(var, 0.f)) + 1e-5f);
    unsigned pk[16];
    #pragma unroll
    for (int c = 0; c < 16; ++c) {
        int c0 = qc * 32 + 2 * c;
        float v0 = (xv[2 * c]     - mu) * inv * g[c0]     + b[c0];
        float v1 = (xv[2 * c + 1] - mu) * inv * g[c0 + 1] + b[c0 + 1];
        pk[c] = (unsigned)bf16r(v0) | ((unsigned)bf16r(v1) << 16);
    }
    uint4* dst = (uint4*)(out + (size_t)pos * 128 + qc * 32);
    #pragma unroll
    for (int q = 0; q < 4; ++q)
        dst[q] = make_uint4(pk[4*q], pk[4*q+1], pk[4*q+2], pk[4*q+3]);
}

// -------- weight repack (co,ci,3,3) f32 -> bf16 [tap][CO][CI] ---------------
__global__ __launch_bounds__(256) void wtrans_kernel(
    const float* __restrict__ w, unsigned short* __restrict__ wT, int CO, int CI)
{
    int gidx = blockIdx.x * 256 + threadIdx.x;   // co*CI + ci
    if (gidx >= CO * CI) return;
    const float* src = w + (size_t)gidx * 9;
    #pragma unroll
    for (int k = 0; k < 9; ++k)
        wT[(size_t)k * CO * CI + gidx] = bf16r(src[k]);
}

// ---------------- bf16 MFMA implicit-GEMM 3x3 conv --------------------------
// in:  [SP][CI] bf16.  wT: [9][CO][CI] bf16.
// block: 2 y-rows x 64 x x 64 co; 4 waves = (wm: y-row) x (wn: co-half).
// wave tile: 64 spatial x 32 co = acc[4][2] of 16x16 frags.
// MODE 0: out bf16 [SP][CO], +bias, leaky.  MODE 1: out f32 [CO][SP], +bias.
template<int CI, int CO, int MODE>
__global__ __launch_bounds__(256) void conv_mfma_kernel(
    const unsigned short* __restrict__ in, const unsigned short* __restrict__ wT,
    const float* __restrict__ bias, void* __restrict__ outp)
{
    __shared__ char smem[4*66*40*2 + 9*64*32*2];    // 21120 + 36864 = 57984 B
    unsigned short (*in_s)[66][40] = (unsigned short (*)[66][40])smem;          // [yy][xx][ci]
    unsigned short (*ws_s)[64][32] = (unsigned short (*)[64][32])(smem + 21120); // [tap][co][ci]

    const int x0  = blockIdx.x * 64;
    const int y0  = blockIdx.y * 2;
    const int co0 = blockIdx.z * 64;
    const int tid = threadIdx.x;
    const int lane = tid & 63, wave = tid >> 6;
    const int wm = wave & 1, wn = wave >> 1;
    const int lrow = lane & 15, kb = lane >> 4;

    f32x4 acc[4][2];
    #pragma unroll
    for (int i = 0; i < 4; ++i)
        #pragma unroll
        for (int j = 0; j < 2; ++j) acc[i][j] = (f32x4){0.f, 0.f, 0.f, 0.f};

    for (int cc = 0; cc < CI / 32; ++cc) {
        // stage input halo tile: 4 rows x 66 x x 32 ci (16B units)
        for (int idx = tid; idx < 1056; idx += 256) {
            int r = idx >> 2, p = idx & 3;
            int yy = r / 66, xx = r % 66;
            int gy = y0 + yy - 1, gx = x0 + xx - 1;
            uint4 val = make_uint4(0u, 0u, 0u, 0u);
            if ((unsigned)gy < 192u && (unsigned)gx < 192u)
                val = *(const uint4*)&in[((size_t)gy * 192 + gx) * CI + cc * 32 + p * 8];
            *(uint4*)&in_s[yy][xx][p * 8] = val;
        }
        // stage weights: 9 taps x 64 co x 32 ci
        for (int idx = tid; idx < 2304; idx += 256) {
            int r = idx >> 2, p = idx & 3;
            int tap = r >> 6, co = r & 63;
            *(uint4*)&ws_s[tap][co][p * 8] =
                *(const uint4*)&wT[((size_t)tap * CO + co0 + co) * CI + cc * 32 + p * 8];
        }
        __syncthreads();
        #pragma unroll
        for (int ky = 0; ky < 3; ++ky) {
            #pragma unroll
            for (int kx = 0; kx < 3; ++kx) {
                short8v b0 = *(const short8v*)&ws_s[ky * 3 + kx][wn * 32 + lrow][kb * 8];
                short8v b1 = *(const short8v*)&ws_s[ky * 3 + kx][wn * 32 + 16 + lrow][kb * 8];
                #pragma unroll
                for (int fm = 0; fm < 4; ++fm) {
                    short8v a = *(const short8v*)&in_s[wm + ky][fm * 16 + lrow + kx][kb * 8];
                    acc[fm][0] = __builtin_amdgcn_mfma_f32_16x16x32_bf16(a, b0, acc[fm][0], 0, 0, 0);
                    acc[fm][1] = __builtin_amdgcn_mfma_f32_16x16x32_bf16(a, b1, acc[fm][1], 0, 0, 0);
                }
            }
        }
        __syncthreads();
    }

    if (MODE == 0) {
        unsigned short* out = (unsigned short*)outp;
        const int y = y0 + wm;
        #pragma unroll
        for (int fn = 0; fn < 2; ++fn) {
            int co = co0 + wn * 32 + fn * 16 + lrow;
            float bb = bias[co];
            #pragma unroll
            for (int fm = 0; fm < 4; ++fm) {
                #pragma unroll
                for (int r = 0; r < 4; ++r) {
                    int i = fm * 16 + kb * 4 + r;
                    float v = acc[fm][fn][r] + bb;
                    v = (v >= 0.f) ? v : 0.01f * v;
                    out[((size_t)y * 192 + x0 + i) * CO + co] = bf16r(v);
                }
            }
        }
    } else {
        float* out = (float*)outp;
        __syncthreads();
        float (*et)[64][65] = (float (*)[64][65])smem;     // 33280 B, aliases staging
        #pragma unroll
        for (int fn = 0; fn < 2; ++fn)
            #pragma unroll
            for (int fm = 0; fm < 4; ++fm)
                #pragma unroll
                for (int r = 0; r < 4; ++r)
                    et[wm][fm * 16 + kb * 4 + r][wn * 32 + fn * 16 + lrow] = acc[fm][fn][r];
        __syncthreads();
        int row = tid >> 1;                 // 0..127 = (yloc, co)
        int yloc = row >> 6, co = row & 63;
        int xh = (tid & 1) * 32;
        float bb = bias[co0 + co];
        #pragma unroll
        for (int q = 0; q < 8; ++q) {
            float4 v;
            v.x = et[yloc][xh + q * 4 + 0][co] + bb;
            v.y = et[yloc][xh + q * 4 + 1][co] + bb;
            v.z = et[yloc][xh + q * 4 + 2][co] + bb;
            v.w = et[yloc][xh + q * 4 + 3][co] + bb;
            *(float4*)&out[(size_t)(co0 + co) * SP + (y0 + yloc) * 192 + x0 + xh + q * 4] = v;
        }
    }
}

// ---------------------------------------------------------------------------
extern "C" void kernel_launch(void* const* d_in, const int* in_sizes, int n_in,
                              void* d_out, int out_size, void* d_ws, size_t ws_size,
                              hipStream_t stream)
{
    const float* x_in    = (const float*)d_in[0];
    const float* ln_g    = (const float*)d_in[1];
    const float* ln_b    = (const float*)d_in[2];
    const float* Wq      = (const float*)d_in[3];
    const float* Wkv     = (const float*)d_in[4];
    const float* Wproj   = (const float*)d_in[5];
    const float* lnl_g   = (const float*)d_in[6];
    const float* lnl_b   = (const float*)d_in[7];
    const float* lng_g   = (const float*)d_in[8];
    const float* lng_b   = (const float*)d_in[9];
    const float* Wo      = (const float*)d_in[10];
    const float* bo      = (const float*)d_in[11];
    const float* cln_g   = (const float*)d_in[12];
    const float* cln_b   = (const float*)d_in[13];
    const float* conv1_w = (const float*)d_in[14];
    const float* conv1_b = (const float*)d_in[15];
    const float* conv2_w = (const float*)d_in[16];
    const float* conv2_b = (const float*)d_in[17];

    float* X = (float*)d_out;                   // running activation (c-major)
    char* ws = (char*)d_ws;
    const size_t SZ_AO = 37748736;              // (36864,256) f32
    float* AO  = (float*)(ws);                  // attn out; first half doubles as XN
    float* XN  = AO;
    float* Qb  = (float*)(ws + SZ_AO);
    float* Kb  = Qb + 9437184;
    float* Vb  = Kb + 9437184;
    float* GK  = Vb + 9437184;
    float* GV  = GK + 49152;
    // conv-phase aliases (attn buffers dead during conv)
    unsigned short* HID16 = (unsigned short*)AO;   // [36864][512] bf16 = 37.75MB (exact)
    unsigned short* XNc16 = (unsigned short*)Qb;   // [36864][128] bf16 = 9.44MB
    unsigned short* wT1   = (unsigned short*)Kb;   // [9][512][128] bf16 = 1.18MB
    unsigned short* wT2   = wT1 + 9 * 512 * 128;   // [9][128][512] bf16 = 1.18MB

    hipMemcpyAsync(X, x_in, (size_t)SP * NC * 4, hipMemcpyDeviceToDevice, stream);

    const float qscale = 0.17677669529663687f;  // 32^-0.5

    for (int l = 0; l < 2; ++l) {
        for (int a = 0; a < 2; ++a) {
            int la = l * 2 + a;
            ln_rows_kernel<<<144, 256, 0, stream>>>(X, ln_g + la * 128, ln_b + la * 128, XN, a);
            gemm_kernel<<<dim3(4, 576), 256, 0, stream>>>(
                XN, Wq + (size_t)la * 128 * 256, 128, 256, 0, qscale, nullptr, Qb, nullptr, a);
            gemm_kernel<<<dim3(8, 576), 256, 0, stream>>>(
                XN, Wkv + (size_t)la * 128 * 512, 128, 512, 1, 1.f, nullptr, Kb, Vb, a);
            proj_gkv_kernel<<<1536, 256, 0, stream>>>(
                Kb, Vb, Wproj + la * 32, lng_g + la * 32, lng_b + la * 32, GK, GV);
            lkln_kernel<<<36864, 256, 0, stream>>>(Kb, lnl_g + la * 32, lnl_b + la * 32);
            attn_kernel<<<1536, 192, 0, stream>>>(Qb, Kb, Vb, GK, GV, AO);
            gemm_kernel<<<dim3(2, 576), 256, 0, stream>>>(
                AO, Wo + (size_t)la * 256 * 128, 256, 128, 2, 1.f, bo + la * 128, X, nullptr, a);
        }
        chanln_bf16_kernel<<<576, 256, 0, stream>>>(X, cln_g + l * 128, cln_b + l * 128, XNc16);
        wtrans_kernel<<<256, 256, 0, stream>>>(conv1_w + (size_t)l * 512 * 128 * 9, wT1, 512, 128);
        wtrans_kernel<<<256, 256, 0, stream>>>(conv2_w + (size_t)l * 128 * 512 * 9, wT2, 128, 512);
        conv_mfma_kernel<128, 512, 0><<<dim3(3, 96, 8), 256, 0, stream>>>(
            XNc16, wT1, conv1_b + l * 512, (void*)HID16);
        conv_mfma_kernel<512, 128, 1><<<dim3(3, 96, 2), 256, 0, stream>>>(
            HID16, wT2, conv2_b + l * 128, (void*)X);
    }
}

// Round 3
// 1297.915 us; speedup vs baseline: 4.0898x; 1.7914x over previous
//
#include <hip/hip_runtime.h>
#include <math.h>

#define SP 36864            // 192*192 spatial
#define NC 128              // model dim

typedef unsigned short u16;
typedef __attribute__((ext_vector_type(8))) short short8v;   // 8 bf16 (4 VGPRs)
typedef __attribute__((ext_vector_type(4))) float f32x4;

static __device__ __forceinline__ u16 bf16r(float f) {
    unsigned u = __builtin_bit_cast(unsigned, f);
    u += 0x7fffu + ((u >> 16) & 1u);            // round-to-nearest-even
    return (u16)(u >> 16);
}
static __device__ __forceinline__ float b2f(u16 u) {
    unsigned v = ((unsigned)u) << 16;
    return __builtin_bit_cast(float, v);
}

// ---------------- LayerNorm over channel -> XN bf16 [row][128] --------------
// perm==0: row=(b*192+t), X addr = c*SP + t*192 + b
// perm==1: row=(b*192+t), X addr = c*SP + b*192 + t
__global__ __launch_bounds__(256) void ln_rows_bf16_kernel(
    const float* __restrict__ X, const float* __restrict__ g,
    const float* __restrict__ b, u16* __restrict__ XN, int perm)
{
    int gid = blockIdx.x * 256 + threadIdx.x;      // 0..36863
    int i0 = gid % 192, i1 = gid / 192;
    int sp = i1 * 192 + i0;                        // coalesced along i0
    int row = (perm == 0) ? (i0 * 192 + i1) : gid;
    float sum = 0.f, sq = 0.f;
    for (int c = 0; c < NC; ++c) {
        float v = X[(size_t)c * SP + sp];
        sum += v; sq += v * v;
    }
    float mu  = sum * (1.f / NC);
    float var = sq * (1.f / NC) - mu * mu;
    float rs  = rsqrtf(var + 1e-5f);
    u16* xr = XN + (size_t)row * NC;
    for (int c0 = 0; c0 < 16; ++c0) {
        unsigned pk[4];
        #pragma unroll
        for (int e = 0; e < 4; ++e) {
            int c = c0 * 8 + e * 2;
            float v0 = (X[(size_t)c * SP + sp]       - mu) * rs * g[c]     + b[c];
            float v1 = (X[(size_t)(c + 1) * SP + sp] - mu) * rs * g[c + 1] + b[c + 1];
            pk[e] = (unsigned)bf16r(v0) | ((unsigned)bf16r(v1) << 16);
        }
        *(uint4*)&xr[c0 * 8] = make_uint4(pk[0], pk[1], pk[2], pk[3]);
    }
}

// -------- weight repack f32 [K][N] -> bf16 [N][K], batched over blockIdx.y --
__global__ __launch_bounds__(256) void repack_t_kernel(
    const float* __restrict__ in, u16* __restrict__ out, int K, int N)
{
    const float* ib = in + (size_t)blockIdx.y * K * N;
    u16* ob = out + (size_t)blockIdx.y * K * N;
    int o = blockIdx.x * 256 + threadIdx.x;
    if (o >= K * N) return;
    int n = o / K, k = o - n * K;
    ob[o] = bf16r(ib[(size_t)k * N + n]);
}

// ---------------- bf16 MFMA GEMM: A[M][KD] @ BT[N][KD]^T --------------------
// tile 128m x 64n, 4 waves (32m x 64n each), BK=64, swizzled LDS.
// MODE 0: Q epilogue (scale, -> O0[bh][t][32]); MODE 1: KV epilogue.
template<int KD, int MODE>
__global__ __launch_bounds__(256) void gemm_qkv_kernel(
    const u16* __restrict__ A, const u16* __restrict__ BT,
    u16* __restrict__ O0, u16* __restrict__ O1, float scale)
{
    __shared__ __align__(16) u16 As[128 * 64];
    __shared__ __align__(16) u16 Bs[64 * 64];
    const int m0 = blockIdx.y * 128, n0 = blockIdx.x * 64;
    const int tid = threadIdx.x, lane = tid & 63, wave = tid >> 6;
    const int lrow = lane & 15, g = lane >> 4;
    f32x4 acc[2][4];
    #pragma unroll
    for (int i = 0; i < 2; ++i)
        #pragma unroll
        for (int j = 0; j < 4; ++j) acc[i][j] = (f32x4){0.f, 0.f, 0.f, 0.f};

    for (int k0 = 0; k0 < KD; k0 += 64) {
        #pragma unroll
        for (int i = 0; i < 4; ++i) {
            int F = tid + i * 256;
            int row = F >> 3, wn = (F & 7) * 16;
            int sw = wn ^ ((row & 7) << 4);
            *(uint4*)&As[F * 8] = *(const uint4*)&A[(size_t)(m0 + row) * KD + k0 + (sw >> 1)];
        }
        #pragma unroll
        for (int i = 0; i < 2; ++i) {
            int F = tid + i * 256;
            int n = F >> 3, wn = (F & 7) * 16;
            int sw = wn ^ ((n & 7) << 4);
            *(uint4*)&Bs[F * 8] = *(const uint4*)&BT[(size_t)(n0 + n) * KD + k0 + (sw >> 1)];
        }
        __syncthreads();
        #pragma unroll
        for (int ks = 0; ks < 2; ++ks) {
            short8v af[2], bf[4];
            #pragma unroll
            for (int mt = 0; mt < 2; ++mt) {
                int row = wave * 32 + mt * 16 + lrow;
                int off = ((ks * 64 + g * 16) ^ ((row & 7) << 4)) >> 1;
                af[mt] = *(const short8v*)&As[row * 64 + off];
            }
            #pragma unroll
            for (int nt = 0; nt < 4; ++nt) {
                int n = nt * 16 + lrow;
                int off = ((ks * 64 + g * 16) ^ ((n & 7) << 4)) >> 1;
                bf[nt] = *(const short8v*)&Bs[n * 64 + off];
            }
            #pragma unroll
            for (int mt = 0; mt < 2; ++mt)
                #pragma unroll
                for (int nt = 0; nt < 4; ++nt)
                    acc[mt][nt] = __builtin_amdgcn_mfma_f32_16x16x32_bf16(
                        af[mt], bf[nt], acc[mt][nt], 0, 0, 0);
        }
        __syncthreads();
    }
    #pragma unroll
    for (int mt = 0; mt < 2; ++mt) {
        #pragma unroll
        for (int r = 0; r < 4; ++r) {
            int m = m0 + wave * 32 + mt * 16 + 4 * g + r;
            int bq = m / 192, t = m - bq * 192;
            #pragma unroll
            for (int nt = 0; nt < 4; ++nt) {
                int n = n0 + nt * 16 + lrow;
                float v = acc[mt][nt][r];
                if (MODE == 0) {
                    O0[((size_t)(bq * 8 + (n >> 5)) * 192 + t) * 32 + (n & 31)] = bf16r(v * scale);
                } else {
                    u16* dst = (n < 256) ? O0 : O1;
                    int nn = n & 255;
                    dst[((size_t)(bq * 8 + (nn >> 5)) * 192 + t) * 32 + (nn & 31)] = bf16r(v);
                }
            }
        }
    }
}

// ---------------- Wo GEMM: AO[36864][256] @ WoT[128][256]^T + bias -> X -----
// PERM0 uses row-permuted logical m so X writes are coalesced for both perms.
template<int PERM>
__global__ __launch_bounds__(256) void gemm_wo_kernel(
    const u16* __restrict__ A, const u16* __restrict__ BT,
    const float* __restrict__ bias, float* __restrict__ X)
{
    __shared__ __align__(16) char smem[64 * 132 * 4];    // 33792 B
    u16* As = (u16*)smem;                 // [128][64]
    u16* Bs = (u16*)(smem + 16384);       // [64][64]
    float (*et)[132] = (float (*)[132])smem;
    const int m0 = blockIdx.y * 128, n0 = blockIdx.x * 64;
    const int tid = threadIdx.x, lane = tid & 63, wave = tid >> 6;
    const int lrow = lane & 15, g = lane >> 4;
    f32x4 acc[2][4];
    #pragma unroll
    for (int i = 0; i < 2; ++i)
        #pragma unroll
        for (int j = 0; j < 4; ++j) acc[i][j] = (f32x4){0.f, 0.f, 0.f, 0.f};

    for (int k0 = 0; k0 < 256; k0 += 64) {
        #pragma unroll
        for (int i = 0; i < 4; ++i) {
            int F = tid + i * 256;
            int row = F >> 3, wn = (F & 7) * 16;
            int sw = wn ^ ((row & 7) << 4);
            int ml = m0 + row;
            int ra = (PERM == 0) ? ((ml % 192) * 192 + ml / 192) : ml;
            *(uint4*)&As[F * 8] = *(const uint4*)&A[(size_t)ra * 256 + k0 + (sw >> 1)];
        }
        #pragma unroll
        for (int i = 0; i < 2; ++i) {
            int F = tid + i * 256;
            int n = F >> 3, wn = (F & 7) * 16;
            int sw = wn ^ ((n & 7) << 4);
            *(uint4*)&Bs[F * 8] = *(const uint4*)&BT[(size_t)(n0 + n) * 256 + k0 + (sw >> 1)];
        }
        __syncthreads();
        #pragma unroll
        for (int ks = 0; ks < 2; ++ks) {
            short8v af[2], bf[4];
            #pragma unroll
            for (int mt = 0; mt < 2; ++mt) {
                int row = wave * 32 + mt * 16 + lrow;
                int off = ((ks * 64 + g * 16) ^ ((row & 7) << 4)) >> 1;
                af[mt] = *(const short8v*)&As[row * 64 + off];
            }
            #pragma unroll
            for (int nt = 0; nt < 4; ++nt) {
                int n = nt * 16 + lrow;
                int off = ((ks * 64 + g * 16) ^ ((n & 7) << 4)) >> 1;
                bf[nt] = *(const short8v*)&Bs[n * 64 + off];
            }
            #pragma unroll
            for (int mt = 0; mt < 2; ++mt)
                #pragma unroll
                for (int nt = 0; nt < 4; ++nt)
                    acc[mt][nt] = __builtin_amdgcn_mfma_f32_16x16x32_bf16(
                        af[mt], bf[nt], acc[mt][nt], 0, 0, 0);
        }
        __syncthreads();
    }
    __syncthreads();
    #pragma unroll
    for (int mt = 0; mt < 2; ++mt)
        #pragma unroll
        for (int nt = 0; nt < 4; ++nt)
            #pragma unroll
            for (int r = 0; r < 4; ++r)
                et[nt * 16 + lrow][wave * 32 + mt * 16 + 4 * g + r] = acc[mt][nt][r];
    __syncthreads();
    int nl = tid >> 2, mseg = (tid & 3) * 32;
    float bb = bias[n0 + nl];
    #pragma unroll
    for (int q = 0; q < 8; ++q) {
        float4 v;
        v.x = et[nl][mseg + q * 4 + 0] + bb;
        v.y = et[nl][mseg + q * 4 + 1] + bb;
        v.z = et[nl][mseg + q * 4 + 2] + bb;
        v.w = et[nl][mseg + q * 4 + 3] + bb;
        *(float4*)&X[(size_t)(n0 + nl) * SP + m0 + mseg + q * 4] = v;
    }
}

// ------ dynamic projection + landmark + fused lk-LayerNorm (bf16 K/V) -------
__global__ __launch_bounds__(256) void proj_lkln_kernel(
    u16* __restrict__ Kb, const u16* __restrict__ Vb,
    const float* __restrict__ wp, const float* __restrict__ lnl_g,
    const float* __restrict__ lnl_b, const float* __restrict__ lng_g,
    const float* __restrict__ lng_b, float* __restrict__ GK, float* __restrict__ GV)
{
    int bh = blockIdx.x, tid = threadIdx.x;
    size_t base = (size_t)bh * 6144;
    __shared__ float wps[32], sc[192], red[1], gkr[32];
    if (tid < 32) wps[tid] = wp[tid];
    __syncthreads();
    float kr[32]; float ksum = 0.f, ksq = 0.f;
    if (tid < 192) {
        float s = 0.f;
        #pragma unroll
        for (int p2 = 0; p2 < 4; ++p2) {
            short8v kv = *(const short8v*)&Kb[base + tid * 32 + p2 * 8];
            #pragma unroll
            for (int j = 0; j < 8; ++j) {
                float v = b2f((u16)kv[j]);
                kr[p2 * 8 + j] = v; s += v * wps[p2 * 8 + j];
                ksum += v; ksq += v * v;
            }
        }
        sc[tid] = s;
    }
    __syncthreads();
    if (tid < 64) {
        float m = fmaxf(fmaxf(sc[tid], sc[tid + 64]), sc[tid + 128]);
        for (int o = 32; o; o >>= 1) m = fmaxf(m, __shfl_xor(m, o));
        if (!tid) red[0] = m;
    }
    __syncthreads();
    float mx = red[0];
    if (tid < 192) sc[tid] = __expf(sc[tid] - mx);
    __syncthreads();
    if (tid < 64) {
        float s2 = sc[tid] + sc[tid + 64] + sc[tid + 128];
        for (int o = 32; o; o >>= 1) s2 += __shfl_xor(s2, o);
        if (!tid) red[0] = s2;
    }
    __syncthreads();
    float invs = 1.f / red[0];
    if (tid < 192) sc[tid] *= invs;
    __syncthreads();
    if (tid < 32) {
        float ka = 0.f, va = 0.f;
        for (int t = 0; t < 192; ++t) {
            float p = sc[t];
            ka += p * b2f(Kb[base + t * 32 + tid]);
            va += p * b2f(Vb[base + t * 32 + tid]);
        }
        gkr[tid] = ka;
        GV[(size_t)bh * 32 + tid] = va;
    }
    __syncthreads();
    if (tid < 32) {
        float mu = 0.f;
        for (int d = 0; d < 32; ++d) mu += gkr[d];
        mu *= (1.f / 32);
        float var = 0.f;
        for (int d = 0; d < 32; ++d) { float df = gkr[d] - mu; var += df * df; }
        var *= (1.f / 32);
        float rs = rsqrtf(var + 1e-5f);
        GK[(size_t)bh * 32 + tid] = (gkr[tid] - mu) * rs * lng_g[tid] + lng_b[tid];
    }
    __syncthreads();                 // raw K fully consumed; safe to overwrite
    if (tid < 192) {
        float mu = ksum * (1.f / 32);
        float var = ksq * (1.f / 32) - mu * mu;
        float rs = rsqrtf(var + 1e-5f);
        #pragma unroll
        for (int p2 = 0; p2 < 4; ++p2) {
            unsigned pk[4];
            #pragma unroll
            for (int e = 0; e < 4; ++e) {
                int c = p2 * 8 + e * 2;
                float v0 = (kr[c]     - mu) * rs * lnl_g[c]     + lnl_b[c];
                float v1 = (kr[c + 1] - mu) * rs * lnl_g[c + 1] + lnl_b[c + 1];
                pk[e] = (unsigned)bf16r(v0) | ((unsigned)bf16r(v1) << 16);
            }
            *(uint4*)&Kb[base + tid * 32 + p2 * 8] = make_uint4(pk[0], pk[1], pk[2], pk[3]);
        }
    }
}

// ---------------- MFMA windowed attention + landmark ------------------------
// block per (b,h); 4 waves; swapped QK^T so softmax is lane-local.
__global__ __launch_bounds__(256) void attn_mfma_kernel(
    const u16* __restrict__ Q, const u16* __restrict__ K, const u16* __restrict__ V,
    const float* __restrict__ GK, const float* __restrict__ GV, u16* __restrict__ AO)
{
    __shared__ __align__(16) u16 Ks[192][40];
    __shared__ __align__(16) u16 VTs[32][200];
    __shared__ __align__(16) u16 Ps[4][16][200];
    __shared__ float gks[32], gvs[32], sgs[192];
    const int bh = blockIdx.x, tid = threadIdx.x;
    const int lane = tid & 63, wave = tid >> 6, lrow = lane & 15, g = lane >> 4;
    const size_t base = (size_t)bh * 6144;

    if (tid < 32) { gks[tid] = GK[(size_t)bh * 32 + tid]; gvs[tid] = GV[(size_t)bh * 32 + tid]; }
    __syncthreads();
    #pragma unroll
    for (int i = 0; i < 3; ++i) {
        int f = tid + i * 256;             // 768 16B chunks
        int key = f >> 2, part = f & 3;
        *(uint4*)&Ks[key][part * 8] = *(const uint4*)&K[base + key * 32 + part * 8];
        uint4 vv = *(const uint4*)&V[base + key * 32 + part * 8];
        u16 tmp[8]; *(uint4*)tmp = vv;
        #pragma unroll
        for (int e = 0; e < 8; ++e) VTs[part * 8 + e][key] = tmp[e];
    }
    if (tid < 192) {
        float s = 0.f;
        #pragma unroll
        for (int p2 = 0; p2 < 4; ++p2) {
            short8v qv = *(const short8v*)&Q[base + tid * 32 + p2 * 8];
            #pragma unroll
            for (int j = 0; j < 8; ++j) s += b2f((u16)qv[j]) * gks[p2 * 8 + j];
        }
        sgs[tid] = s;
    }
    __syncthreads();

    for (int qi = 0; qi < 3; ++qi) {
        int qt = wave * 3 + qi;
        int q = qt * 16 + lrow;
        int ww = qt >> 2;
        int tlo = (ww == 0) ? 0 : (ww - 1) * 4;
        int thi = (ww == 2) ? 12 : (ww + 2) * 4;
        short8v qf = *(const short8v*)&Q[base + q * 32 + g * 8];
        f32x4 s[12];
        #pragma unroll
        for (int t = 0; t < 12; ++t) {
            if (t >= tlo && t < thi) {
                short8v kf = *(const short8v*)&Ks[t * 16 + lrow][g * 8];
                f32x4 z = (f32x4){0.f, 0.f, 0.f, 0.f};
                s[t] = __builtin_amdgcn_mfma_f32_16x16x32_bf16(kf, qf, z, 0, 0, 0);
            }
        }
        float sg = sgs[q];
        float m = sg;
        #pragma unroll
        for (int t = 0; t < 12; ++t) if (t >= tlo && t < thi)
            m = fmaxf(m, fmaxf(fmaxf(s[t][0], s[t][1]), fmaxf(s[t][2], s[t][3])));
        m = fmaxf(m, __shfl_xor(m, 16));
        m = fmaxf(m, __shfl_xor(m, 32));
        float l = 0.f;
        #pragma unroll
        for (int t = 0; t < 12; ++t) if (t >= tlo && t < thi) {
            #pragma unroll
            for (int r = 0; r < 4; ++r) { float p = __expf(s[t][r] - m); s[t][r] = p; l += p; }
        }
        l += __shfl_xor(l, 16);
        l += __shfl_xor(l, 32);
        float eg = __expf(sg - m);
        float inv = 1.f / (l + eg);
        float pgv = eg * inv;
        #pragma unroll
        for (int t = 0; t < 12; ++t) if (t >= tlo && t < thi) {
            unsigned u0 = (unsigned)bf16r(s[t][0] * inv) | ((unsigned)bf16r(s[t][1] * inv) << 16);
            unsigned u1 = (unsigned)bf16r(s[t][2] * inv) | ((unsigned)bf16r(s[t][3] * inv) << 16);
            *(uint2*)&Ps[wave][lrow][t * 16 + g * 4] = make_uint2(u0, u1);
        }
        f32x4 o[2] = {(f32x4){0.f,0.f,0.f,0.f}, (f32x4){0.f,0.f,0.f,0.f}};
        int slo = tlo >> 1, shi = thi >> 1;
        #pragma unroll
        for (int ss = 0; ss < 6; ++ss) if (ss >= slo && ss < shi) {
            short8v pa = *(const short8v*)&Ps[wave][lrow][ss * 32 + g * 8];
            #pragma unroll
            for (int dt = 0; dt < 2; ++dt) {
                short8v vb = *(const short8v*)&VTs[dt * 16 + lrow][ss * 32 + g * 8];
                o[dt] = __builtin_amdgcn_mfma_f32_16x16x32_bf16(pa, vb, o[dt], 0, 0, 0);
            }
        }
        int b = bh >> 3, h = bh & 7;
        #pragma unroll
        for (int r = 0; r < 4; ++r) {
            int qg = qt * 16 + 4 * g + r;
            float pg = __shfl(pgv, 4 * g + r);
            size_t rowbase = ((size_t)b * 192 + qg) * 256 + h * 32;
            #pragma unroll
            for (int dt = 0; dt < 2; ++dt) {
                int d = dt * 16 + lrow;
                AO[rowbase + d] = bf16r(o[dt][r] + pg * gvs[d]);
            }
        }
    }
}

// -------- ChanLayerNorm -> bf16 [sp][128] (conv1 input) ---------------------
__global__ __launch_bounds__(256) void chanln_bf16_kernel(
    const float* __restrict__ X, const float* __restrict__ g,
    const float* __restrict__ b, u16* __restrict__ out)
{
    int tid = threadIdx.x;
    int p = tid >> 2, qc = tid & 3;
    int pos = blockIdx.x * 64 + p;
    float xv[32];
    float sum = 0.f, sumsq = 0.f;
    #pragma unroll
    for (int c = 0; c < 32; ++c) {
        float v = X[(size_t)(qc * 32 + c) * SP + pos];
        xv[c] = v; sum += v; sumsq += v * v;
    }
    sum += __shfl_xor(sum, 1);  sum += __shfl_xor(sum, 2);
    sumsq += __shfl_xor(sumsq, 1); sumsq += __shfl_xor(sumsq, 2);
    float mu  = sum * (1.f / 128);
    float var = sumsq * (1.f / 128) - mu * mu;
    float inv = 1.f / (sqrtf(fmaxf(var, 0.f)) + 1e-5f);
    unsigned pk[16];
    #pragma unroll
    for (int c = 0; c < 16; ++c) {
        int c0 = qc * 32 + 2 * c;
        float v0 = (xv[2 * c]     - mu) * inv * g[c0]     + b[c0];
        float v1 = (xv[2 * c + 1] - mu) * inv * g[c0 + 1] + b[c0 + 1];
        pk[c] = (unsigned)bf16r(v0) | ((unsigned)bf16r(v1) << 16);
    }
    uint4* dst = (uint4*)(out + (size_t)pos * 128 + qc * 32);
    #pragma unroll
    for (int q = 0; q < 4; ++q)
        dst[q] = make_uint4(pk[4*q], pk[4*q+1], pk[4*q+2], pk[4*q+3]);
}

// -------- conv weight repack (co,ci,3,3) f32 -> bf16 [tap][CO][CI], batched -
__global__ __launch_bounds__(256) void wtrans_kernel(
    const float* __restrict__ w, u16* __restrict__ wT, int CO, int CI)
{
    const float* wb = w + (size_t)blockIdx.y * CO * CI * 9;
    u16* wTb = wT + (size_t)blockIdx.y * CO * CI * 9;
    int gidx = blockIdx.x * 256 + threadIdx.x;   // co*CI + ci
    if (gidx >= CO * CI) return;
    const float* src = wb + (size_t)gidx * 9;
    #pragma unroll
    for (int k = 0; k < 9; ++k)
        wTb[(size_t)k * CO * CI + gidx] = bf16r(src[k]);
}

// ---------------- bf16 MFMA implicit-GEMM 3x3 conv --------------------------
template<int CI, int CO, int MODE>
__global__ __launch_bounds__(256) void conv_mfma_kernel(
    const u16* __restrict__ in, const u16* __restrict__ wT,
    const float* __restrict__ bias, void* __restrict__ outp)
{
    __shared__ __align__(16) char smem[4*66*40*2 + 9*64*32*2];
    u16 (*in_s)[66][40] = (u16 (*)[66][40])smem;
    u16 (*ws_s)[64][32] = (u16 (*)[64][32])(smem + 21120);

    const int x0  = blockIdx.x * 64;
    const int y0  = blockIdx.y * 2;
    const int co0 = blockIdx.z * 64;
    const int tid = threadIdx.x;
    const int lane = tid & 63, wave = tid >> 6;
    const int wm = wave & 1, wn = wave >> 1;
    const int lrow = lane & 15, kb = lane >> 4;

    f32x4 acc[4][2];
    #pragma unroll
    for (int i = 0; i < 4; ++i)
        #pragma unroll
        for (int j = 0; j < 2; ++j) acc[i][j] = (f32x4){0.f, 0.f, 0.f, 0.f};

    for (int cc = 0; cc < CI / 32; ++cc) {
        for (int idx = tid; idx < 1056; idx += 256) {
            int r = idx >> 2, p = idx & 3;
            int yy = r / 66, xx = r % 66;
            int gy = y0 + yy - 1, gx = x0 + xx - 1;
            uint4 val = make_uint4(0u, 0u, 0u, 0u);
            if ((unsigned)gy < 192u && (unsigned)gx < 192u)
                val = *(const uint4*)&in[((size_t)gy * 192 + gx) * CI + cc * 32 + p * 8];
            *(uint4*)&in_s[yy][xx][p * 8] = val;
        }
        for (int idx = tid; idx < 2304; idx += 256) {
            int r = idx >> 2, p = idx & 3;
            int tap = r >> 6, co = r & 63;
            *(uint4*)&ws_s[tap][co][p * 8] =
                *(const uint4*)&wT[((size_t)tap * CO + co0 + co) * CI + cc * 32 + p * 8];
        }
        __syncthreads();
        #pragma unroll
        for (int ky = 0; ky < 3; ++ky) {
            #pragma unroll
            for (int kx = 0; kx < 3; ++kx) {
                short8v b0 = *(const short8v*)&ws_s[ky * 3 + kx][wn * 32 + lrow][kb * 8];
                short8v b1 = *(const short8v*)&ws_s[ky * 3 + kx][wn * 32 + 16 + lrow][kb * 8];
                #pragma unroll
                for (int fm = 0; fm < 4; ++fm) {
                    short8v a = *(const short8v*)&in_s[wm + ky][fm * 16 + lrow + kx][kb * 8];
                    acc[fm][0] = __builtin_amdgcn_mfma_f32_16x16x32_bf16(a, b0, acc[fm][0], 0, 0, 0);
                    acc[fm][1] = __builtin_amdgcn_mfma_f32_16x16x32_bf16(a, b1, acc[fm][1], 0, 0, 0);
                }
            }
        }
        __syncthreads();
    }

    if (MODE == 0) {
        u16* out = (u16*)outp;
        const int y = y0 + wm;
        #pragma unroll
        for (int fn = 0; fn < 2; ++fn) {
            int co = co0 + wn * 32 + fn * 16 + lrow;
            float bb = bias[co];
            #pragma unroll
            for (int fm = 0; fm < 4; ++fm) {
                #pragma unroll
                for (int r = 0; r < 4; ++r) {
                    int i = fm * 16 + kb * 4 + r;
                    float v = acc[fm][fn][r] + bb;
                    v = (v >= 0.f) ? v : 0.01f * v;
                    out[((size_t)y * 192 + x0 + i) * CO + co] = bf16r(v);
                }
            }
        }
    } else {
        float* out = (float*)outp;
        __syncthreads();
        float (*et)[64][65] = (float (*)[64][65])smem;
        #pragma unroll
        for (int fn = 0; fn < 2; ++fn)
            #pragma unroll
            for (int fm = 0; fm < 4; ++fm)
                #pragma unroll
                for (int r = 0; r < 4; ++r)
                    et[wm][fm * 16 + kb * 4 + r][wn * 32 + fn * 16 + lrow] = acc[fm][fn][r];
        __syncthreads();
        int row = tid >> 1;
        int yloc = row >> 6, co = row & 63;
        int xh = (tid & 1) * 32;
        float bb = bias[co0 + co];
        #pragma unroll
        for (int q = 0; q < 8; ++q) {
            float4 v;
            v.x = et[yloc][xh + q * 4 + 0][co] + bb;
            v.y = et[yloc][xh + q * 4 + 1][co] + bb;
            v.z = et[yloc][xh + q * 4 + 2][co] + bb;
            v.w = et[yloc][xh + q * 4 + 3][co] + bb;
            *(float4*)&out[(size_t)(co0 + co) * SP + (y0 + yloc) * 192 + x0 + xh + q * 4] = v;
        }
    }
}

// ---------------------------------------------------------------------------
extern "C" void kernel_launch(void* const* d_in, const int* in_sizes, int n_in,
                              void* d_out, int out_size, void* d_ws, size_t ws_size,
                              hipStream_t stream)
{
    const float* x_in    = (const float*)d_in[0];
    const float* ln_g    = (const float*)d_in[1];
    const float* ln_b    = (const float*)d_in[2];
    const float* Wq      = (const float*)d_in[3];
    const float* Wkv     = (const float*)d_in[4];
    const float* Wproj   = (const float*)d_in[5];
    const float* lnl_g   = (const float*)d_in[6];
    const float* lnl_b   = (const float*)d_in[7];
    const float* lng_g   = (const float*)d_in[8];
    const float* lng_b   = (const float*)d_in[9];
    const float* Wo      = (const float*)d_in[10];
    const float* bo      = (const float*)d_in[11];
    const float* cln_g   = (const float*)d_in[12];
    const float* cln_b   = (const float*)d_in[13];
    const float* conv1_w = (const float*)d_in[14];
    const float* conv1_b = (const float*)d_in[15];
    const float* conv2_w = (const float*)d_in[16];
    const float* conv2_b = (const float*)d_in[17];

    float* X = (float*)d_out;
    char* ws = (char*)d_ws;
    u16*   XN   = (u16*)(ws);                        //  9,437,184 B
    u16*   AO   = (u16*)(ws + 9437184);              // 18,874,368
    u16*   Qb   = (u16*)(ws + 28311552);             // 18,874,368
    u16*   Kb   = (u16*)(ws + 47185920);             // 18,874,368
    u16*   Vb   = (u16*)(ws + 66060288);             // 18,874,368
    float* GK   = (float*)(ws + 84934656);           //    196,608
    float* GV   = (float*)(ws + 85131264);           //    196,608
    u16*   wqT  = (u16*)(ws + 85327872);             //    262,144
    u16*   wkvT = (u16*)(ws + 85590016);             //    524,288
    u16*   woT  = (u16*)(ws + 86114304);             //    262,144
    u16*   wT1  = (u16*)(ws + 86376448);             //  2,359,296
    u16*   wT2  = (u16*)(ws + 88735744);             //  2,359,296
    u16*   XNc16 = XN;                               // conv aliases
    u16*   HID16 = Qb;                               // spans Qb+Kb (37.75MB)

    hipMemcpyAsync(X, x_in, (size_t)SP * NC * 4, hipMemcpyDeviceToDevice, stream);

    repack_t_kernel<<<dim3(128, 4), 256, 0, stream>>>(Wq, wqT, 128, 256);
    repack_t_kernel<<<dim3(256, 4), 256, 0, stream>>>(Wkv, wkvT, 128, 512);
    repack_t_kernel<<<dim3(128, 4), 256, 0, stream>>>(Wo, woT, 256, 128);
    wtrans_kernel<<<dim3(256, 2), 256, 0, stream>>>(conv1_w, wT1, 512, 128);
    wtrans_kernel<<<dim3(256, 2), 256, 0, stream>>>(conv2_w, wT2, 128, 512);

    const float qscale = 0.17677669529663687f;  // 32^-0.5

    for (int l = 0; l < 2; ++l) {
        for (int a = 0; a < 2; ++a) {
            int la = l * 2 + a;
            ln_rows_bf16_kernel<<<144, 256, 0, stream>>>(
                X, ln_g + la * 128, ln_b + la * 128, XN, a);
            gemm_qkv_kernel<128, 0><<<dim3(4, 288), 256, 0, stream>>>(
                XN, wqT + (size_t)la * 32768, Qb, nullptr, qscale);
            gemm_qkv_kernel<128, 1><<<dim3(8, 288), 256, 0, stream>>>(
                XN, wkvT + (size_t)la * 65536, Kb, Vb, 1.f);
            proj_lkln_kernel<<<1536, 256, 0, stream>>>(
                Kb, Vb, Wproj + la * 32, lnl_g + la * 32, lnl_b + la * 32,
                lng_g + la * 32, lng_b + la * 32, GK, GV);
            attn_mfma_kernel<<<1536, 256, 0, stream>>>(Qb, Kb, Vb, GK, GV, AO);
            if (a == 0)
                gemm_wo_kernel<0><<<dim3(2, 288), 256, 0, stream>>>(
                    AO, woT + (size_t)la * 32768, bo + la * 128, X);
            else
                gemm_wo_kernel<1><<<dim3(2, 288), 256, 0, stream>>>(
                    AO, woT + (size_t)la * 32768, bo + la * 128, X);
        }
        chanln_bf16_kernel<<<576, 256, 0, stream>>>(X, cln_g + l * 128, cln_b + l * 128, XNc16);
        conv_mfma_kernel<128, 512, 0><<<dim3(3, 96, 8), 256, 0, stream>>>(
            XNc16, wT1 + (size_t)l * 589824, conv1_b + l * 512, (void*)HID16);
        conv_mfma_kernel<512, 128, 1><<<dim3(3, 96, 2), 256, 0, stream>>>(
            HID16, wT2 + (size_t)l * 589824, conv2_b + l * 128, (void*)X);
    }
}